// Round 1
// baseline (313.667 us; speedup 1.0000x reference)
//
#include <hip/hip_runtime.h>
#include <hip/hip_bf16.h>

#define NN 10000
#define INDIM 128
#define HID 64

typedef __attribute__((ext_vector_type(8))) short bf16x8;
typedef __attribute__((ext_vector_type(4))) float f32x4;

// ---- CSR build ----
__global__ void k_zero(int* __restrict__ cnt) {
  int i = blockIdx.x * 256 + threadIdx.x;
  if (i < NN) cnt[i] = 0;
}

__global__ void k_count(const int* __restrict__ dst, int E, int* __restrict__ cnt) {
  int e = blockIdx.x * 256 + threadIdx.x;
  if (e < E) atomicAdd(&cnt[dst[e]], 1);
}

// single-block scan over NN=10000 counts; also emits cursor copy and deg^-1/2
__global__ __launch_bounds__(1024) void k_scan(const int* __restrict__ cnt, int E,
                                               int* __restrict__ off, int* __restrict__ cursor,
                                               float* __restrict__ dis) {
  __shared__ int sp[1024];
  int t = threadIdx.x;
  const int CH = (NN + 1023) / 1024;  // 10
  int base = t * CH;
  int s = 0;
  #pragma unroll
  for (int i = 0; i < CH; i++) { int idx = base + i; if (idx < NN) s += cnt[idx]; }
  sp[t] = s;
  __syncthreads();
  for (int d = 1; d < 1024; d <<= 1) {   // Hillis-Steele inclusive scan
    int v = (t >= d) ? sp[t - d] : 0;
    __syncthreads();
    sp[t] += v;
    __syncthreads();
  }
  int run = sp[t] - s;                   // exclusive prefix for this chunk
  #pragma unroll
  for (int i = 0; i < CH; i++) {
    int idx = base + i;
    if (idx < NN) {
      off[idx] = run;
      cursor[idx] = run;
      int c = cnt[idx];
      dis[idx] = rsqrtf((float)(c + 1));  // +1 = self loop; always > 0
      run += c;
    }
  }
  if (t == 0) off[NN] = E;
}

__global__ void k_scatter(const int* __restrict__ src, const int* __restrict__ dst, int E,
                          int* __restrict__ cursor, int* __restrict__ csr) {
  int e = blockIdx.x * 256 + threadIdx.x;
  if (e < E) {
    int p = atomicAdd(&cursor[dst[e]], 1);
    csr[p] = src[e];
  }
}

// ---- xws[r][j] = dis[r] * sum_k x[r][k] * W[k][j] ; one wave per row ----
template <int K>
__global__ __launch_bounds__(256) void k_gemm(const float* __restrict__ x,
                                              const float* __restrict__ W,
                                              const float* __restrict__ dis,
                                              float* __restrict__ xws) {
  __shared__ float w[K * HID];
  int t = threadIdx.x;
  for (int i = t; i < K * HID; i += 256) w[i] = W[i];
  __syncthreads();
  int r = blockIdx.x * 4 + (t >> 6);
  int j = t & 63;
  const float* xr = x + (size_t)r * K;
  float acc = 0.f;
  #pragma unroll 8
  for (int k = 0; k < K; k++) acc = fmaf(xr[k], w[k * HID + j], acc);
  xws[(size_t)r * HID + j] = acc * dis[r];
}

// ---- aggregation: h[d] = dis[d]*(xws[d] + sum_in xws[s]) + b ; one wave per node ----
template <bool RELU, bool BF16OUT>
__global__ __launch_bounds__(256) void k_agg(const float* __restrict__ xws,
                                             const int* __restrict__ off,
                                             const int* __restrict__ csr,
                                             const float* __restrict__ dis,
                                             const float* __restrict__ b,
                                             void* __restrict__ hout) {
  int wid = threadIdx.x >> 6, lane = threadIdx.x & 63;
  int d = blockIdx.x * 4 + wid;
  int s0 = off[d], s1 = off[d + 1];
  float acc = xws[(size_t)d * HID + lane];   // self-loop term
  int k = s0;
  for (; k + 4 <= s1; k += 4) {              // 4-deep to break the latency chain
    int i0 = csr[k], i1 = csr[k + 1], i2 = csr[k + 2], i3 = csr[k + 3];
    float v0 = xws[(size_t)i0 * HID + lane];
    float v1 = xws[(size_t)i1 * HID + lane];
    float v2 = xws[(size_t)i2 * HID + lane];
    float v3 = xws[(size_t)i3 * HID + lane];
    acc += v0 + v1 + v2 + v3;
  }
  for (; k < s1; k++) acc += xws[(size_t)csr[k] * HID + lane];
  float v = acc * dis[d] + b[lane];
  if (RELU) v = fmaxf(v, 0.f);
  if (BF16OUT)
    ((__hip_bfloat16*)hout)[(size_t)d * HID + lane] = __float2bfloat16(v);
  else
    ((float*)hout)[(size_t)d * HID + lane] = v;
}

// ---- final: out = sigmoid(h2 @ h2^T), bf16 MFMA, transposed tile store (Z symmetric) ----
__global__ __launch_bounds__(256) void k_final(const short* __restrict__ hb,
                                               float* __restrict__ out) {
  int wid = threadIdx.x >> 6, lane = threadIdx.x & 63;
  int tj = blockIdx.y * 4 + wid;
  if (tj >= NN / 16) return;
  int ti = blockIdx.x;
  int rowbase = ti * 16, colbase = tj * 16;
  int m = lane & 15, q = lane >> 4;
  // A frag: rows rowbase+m, k = 8q..8q+7 (and +32); B = h2^T -> same gather on col rows
  const bf16x8* pa = reinterpret_cast<const bf16x8*>(hb + (size_t)(rowbase + m) * HID + q * 8);
  const bf16x8* pb = reinterpret_cast<const bf16x8*>(hb + (size_t)(colbase + m) * HID + q * 8);
  bf16x8 a0 = pa[0];
  bf16x8 a1 = pa[4];  // +32 elements
  bf16x8 b0 = pb[0];
  bf16x8 b1 = pb[4];
  f32x4 acc = {0.f, 0.f, 0.f, 0.f};
  acc = __builtin_amdgcn_mfma_f32_16x16x32_bf16(a0, b0, acc, 0, 0, 0);
  acc = __builtin_amdgcn_mfma_f32_16x16x32_bf16(a1, b1, acc, 0, 0, 0);
  // C/D map: col = lane&15 (=m), row = 4q + r. Store transposed (Z^T == Z) -> float4.
  f32x4 o;
  #pragma unroll
  for (int r = 0; r < 4; r++) o[r] = 1.0f / (1.0f + __expf(-acc[r]));
  *reinterpret_cast<f32x4*>(out + (size_t)(colbase + m) * NN + rowbase + q * 4) = o;
}

extern "C" void kernel_launch(void* const* d_in, const int* in_sizes, int n_in,
                              void* d_out, int out_size, void* d_ws, size_t ws_size,
                              hipStream_t stream) {
  const float* x  = (const float*)d_in[0];
  const int*   ei = (const int*)d_in[1];
  const float* W1 = (const float*)d_in[2];
  const float* b1 = (const float*)d_in[3];
  const float* W2 = (const float*)d_in[4];
  const float* b2 = (const float*)d_in[5];
  const int E = in_sizes[1] / 2;
  const int* src = ei;
  const int* dst = ei + E;

  // Scratch layout inside d_out (400 MB; everything here is dead before k_final
  // rewrites all of d_out). Only h2(bf16) must live in d_ws: it is read while
  // d_out is being written.
  char* base = (char*)d_out;
  float* xwA  = (float*)(base);                          // 640000 f32 (xw scaled)
  float* hB   = (float*)(base + 2560000);                // 640000 f32 (h1)
  int*   csr  = (int*)(base + 5120000);                  // E ints
  char*  p2   = base + 5120000 + 4 * (size_t)E;
  int*   cnt    = (int*)(p2);
  int*   off    = (int*)(p2 + 40064);
  int*   cursor = (int*)(p2 + 80128);
  float* dis    = (float*)(p2 + 120192);
  __hip_bfloat16* h2b = (__hip_bfloat16*)d_ws;           // 640000 bf16 = 1.28 MB

  k_zero<<<(NN + 255) / 256, 256, 0, stream>>>(cnt);
  k_count<<<(E + 255) / 256, 256, 0, stream>>>(dst, E, cnt);
  k_scan<<<1, 1024, 0, stream>>>(cnt, E, off, cursor, dis);
  k_scatter<<<(E + 255) / 256, 256, 0, stream>>>(src, dst, E, cursor, csr);

  k_gemm<INDIM><<<NN / 4, 256, 0, stream>>>(x, W1, dis, xwA);
  k_agg<true, false><<<NN / 4, 256, 0, stream>>>(xwA, off, csr, dis, b1, hB);
  k_gemm<HID><<<NN / 4, 256, 0, stream>>>(hB, W2, dis, xwA);
  k_agg<false, true><<<NN / 4, 256, 0, stream>>>(xwA, off, csr, dis, b2, h2b);

  dim3 g9(NN / 16, (NN / 16 + 3) / 4);  // 625 x 157
  k_final<<<g9, 256, 0, stream>>>((const short*)h2b, (float*)d_out);
}

// Round 2
// 248.851 us; speedup vs baseline: 1.2605x; 1.2605x over previous
//
#include <hip/hip_runtime.h>
#include <hip/hip_bf16.h>

#define NN 10000
#define INDIM 128
#define HID 64

typedef __attribute__((ext_vector_type(8))) short bf16x8;
typedef __attribute__((ext_vector_type(4))) float f32x4;

// ---- CSR build ----
__global__ void k_zero(int* __restrict__ cnt) {
  int i = blockIdx.x * 256 + threadIdx.x;
  if (i < NN) cnt[i] = 0;
}

__global__ void k_count(const int* __restrict__ dst, int E, int* __restrict__ cnt) {
  int e = blockIdx.x * 256 + threadIdx.x;
  if (e < E) atomicAdd(&cnt[dst[e]], 1);
}

// single-block scan over NN=10000 counts; also emits cursor copy and deg^-1/2
__global__ __launch_bounds__(1024) void k_scan(const int* __restrict__ cnt, int E,
                                               int* __restrict__ off, int* __restrict__ cursor,
                                               float* __restrict__ dis) {
  __shared__ int sp[1024];
  int t = threadIdx.x;
  const int CH = (NN + 1023) / 1024;  // 10
  int base = t * CH;
  int s = 0;
  #pragma unroll
  for (int i = 0; i < CH; i++) { int idx = base + i; if (idx < NN) s += cnt[idx]; }
  sp[t] = s;
  __syncthreads();
  for (int d = 1; d < 1024; d <<= 1) {   // Hillis-Steele inclusive scan
    int v = (t >= d) ? sp[t - d] : 0;
    __syncthreads();
    sp[t] += v;
    __syncthreads();
  }
  int run = sp[t] - s;                   // exclusive prefix for this chunk
  #pragma unroll
  for (int i = 0; i < CH; i++) {
    int idx = base + i;
    if (idx < NN) {
      off[idx] = run;
      cursor[idx] = run;
      int c = cnt[idx];
      dis[idx] = rsqrtf((float)(c + 1));  // +1 = self loop; always > 0
      run += c;
    }
  }
  if (t == 0) off[NN] = E;
}

__global__ void k_scatter(const int* __restrict__ src, const int* __restrict__ dst, int E,
                          int* __restrict__ cursor, int* __restrict__ csr) {
  int e = blockIdx.x * 256 + threadIdx.x;
  if (e < E) {
    int p = atomicAdd(&cursor[dst[e]], 1);
    csr[p] = src[e];
  }
}

// ---- xws[r][j] = dis[r] * sum_k x[r][k] * W[k][j] ; one wave per row ----
// Row x[r] is loaded once per wave as coalesced float2 (whole row lives in the
// wave's registers); inner loop broadcasts via compile-time-lane __shfl -> no
// global-memory latency inside the FMA chain.
template <int K>
__global__ __launch_bounds__(256) void k_gemm(const float* __restrict__ x,
                                              const float* __restrict__ W,
                                              const float* __restrict__ dis,
                                              float* __restrict__ xws) {
  __shared__ float w[K * HID];
  int t = threadIdx.x;
  for (int i = t; i < K * HID; i += 256) w[i] = W[i];
  __syncthreads();
  int r = blockIdx.x * 4 + (t >> 6);
  int j = t & 63;
  float2 xv = ((const float2*)(x + (size_t)r * K))[j & (K / 2 - 1)];
  float acc = 0.f;
  #pragma unroll
  for (int k = 0; k < K; k++) {
    float xk = __shfl((k & 1) ? xv.y : xv.x, k >> 1, 64);
    acc = fmaf(xk, w[k * HID + j], acc);
  }
  xws[(size_t)r * HID + j] = acc * dis[r];
}

// ---- aggregation: h[d] = dis[d]*(xws[d] + sum_in xws[s]) + b ; one wave per node ----
template <bool RELU, bool BF16OUT>
__global__ __launch_bounds__(256) void k_agg(const float* __restrict__ xws,
                                             const int* __restrict__ off,
                                             const int* __restrict__ csr,
                                             const float* __restrict__ dis,
                                             const float* __restrict__ b,
                                             void* __restrict__ hout) {
  int wid = threadIdx.x >> 6, lane = threadIdx.x & 63;
  int d = blockIdx.x * 4 + wid;
  int s0 = off[d], s1 = off[d + 1];
  float acc = xws[(size_t)d * HID + lane];   // self-loop term
  int k = s0;
  for (; k + 4 <= s1; k += 4) {              // 4-deep to break the latency chain
    int i0 = csr[k], i1 = csr[k + 1], i2 = csr[k + 2], i3 = csr[k + 3];
    float v0 = xws[(size_t)i0 * HID + lane];
    float v1 = xws[(size_t)i1 * HID + lane];
    float v2 = xws[(size_t)i2 * HID + lane];
    float v3 = xws[(size_t)i3 * HID + lane];
    acc += v0 + v1 + v2 + v3;
  }
  for (; k < s1; k++) acc += xws[(size_t)csr[k] * HID + lane];
  float v = acc * dis[d] + b[lane];
  if (RELU) v = fmaxf(v, 0.f);
  if (BF16OUT)
    ((__hip_bfloat16*)hout)[(size_t)d * HID + lane] = __float2bfloat16(v);
  else
    ((float*)hout)[(size_t)d * HID + lane] = v;
}

// ---- final: out = sigmoid(h2 @ h2^T) ----
// One wave computes a 64x64 output tile (4x4 accs of 16x16x32 MFMA, K=64) ->
// reads drop to 1 byte per output byte (all L2/L3-resident). Z symmetric, so
// each 16x16 subtile is stored transposed -> contiguous float4 per lane with
// 64B segments per 4-lane group. Nontemporal: don't let the 400MB write
// stream evict h2b from L2.
__global__ __launch_bounds__(256) void k_final(const short* __restrict__ hb,
                                               float* __restrict__ out) {
  const int T = (NN + 63) / 64;  // 157
  int wid = threadIdx.x >> 6, lane = threadIdx.x & 63;
  int tx = blockIdx.x * 2 + (wid & 1);
  int ty = blockIdx.y * 2 + (wid >> 1);
  if (tx >= T || ty >= T) return;
  int rowbase = tx * 64, colbase = ty * 64;
  int m = lane & 15, q = lane >> 4;

  bf16x8 a0[4], a1[4], b0[4], b1[4];
  #pragma unroll
  for (int rt = 0; rt < 4; rt++) {
    int r = rowbase + rt * 16 + m; r = r < NN ? r : NN - 1;
    const bf16x8* p = reinterpret_cast<const bf16x8*>(hb + (size_t)r * HID + q * 8);
    a0[rt] = p[0]; a1[rt] = p[4];
  }
  #pragma unroll
  for (int ct = 0; ct < 4; ct++) {
    int r = colbase + ct * 16 + m; r = r < NN ? r : NN - 1;
    const bf16x8* p = reinterpret_cast<const bf16x8*>(hb + (size_t)r * HID + q * 8);
    b0[ct] = p[0]; b1[ct] = p[4];
  }

  f32x4 acc[4][4];
  #pragma unroll
  for (int rt = 0; rt < 4; rt++)
    #pragma unroll
    for (int ct = 0; ct < 4; ct++) {
      f32x4 z = {0.f, 0.f, 0.f, 0.f};
      z = __builtin_amdgcn_mfma_f32_16x16x32_bf16(a0[rt], b0[ct], z, 0, 0, 0);
      z = __builtin_amdgcn_mfma_f32_16x16x32_bf16(a1[rt], b1[ct], z, 0, 0, 0);
      acc[rt][ct] = z;
    }

  // D[row][col]: row = A-side = rowbase+rt*16+4q+r, col = B-side = colbase+ct*16+m.
  // Transposed store (Z^T == Z): out[col][row].
  #pragma unroll
  for (int rt = 0; rt < 4; rt++)
    #pragma unroll
    for (int ct = 0; ct < 4; ct++) {
      if (rowbase + rt * 16 < NN && colbase + ct * 16 < NN) {  // wave-uniform
        f32x4 z = acc[rt][ct], o;
        #pragma unroll
        for (int r = 0; r < 4; r++)
          o[r] = __builtin_amdgcn_rcpf(1.0f + __expf(-z[r]));
        size_t orow = (size_t)(colbase + ct * 16 + m);
        size_t ocol = (size_t)(rowbase + rt * 16 + q * 4);
        __builtin_nontemporal_store(o, reinterpret_cast<f32x4*>(out + orow * NN + ocol));
      }
    }
}

extern "C" void kernel_launch(void* const* d_in, const int* in_sizes, int n_in,
                              void* d_out, int out_size, void* d_ws, size_t ws_size,
                              hipStream_t stream) {
  const float* x  = (const float*)d_in[0];
  const int*   ei = (const int*)d_in[1];
  const float* W1 = (const float*)d_in[2];
  const float* b1 = (const float*)d_in[3];
  const float* W2 = (const float*)d_in[4];
  const float* b2 = (const float*)d_in[5];
  const int E = in_sizes[1] / 2;
  const int* src = ei;
  const int* dst = ei + E;

  // Scratch layout inside d_out (400 MB; everything here is dead before k_final
  // rewrites all of d_out). Only h2(bf16) must live in d_ws: it is read while
  // d_out is being written.
  char* base = (char*)d_out;
  float* xwA  = (float*)(base);                          // 640000 f32 (xw scaled)
  float* hB   = (float*)(base + 2560000);                // 640000 f32 (h1)
  int*   csr  = (int*)(base + 5120000);                  // E ints
  char*  p2   = base + 5120000 + 4 * (size_t)E;
  int*   cnt    = (int*)(p2);
  int*   off    = (int*)(p2 + 40064);
  int*   cursor = (int*)(p2 + 80128);
  float* dis    = (float*)(p2 + 120192);
  __hip_bfloat16* h2b = (__hip_bfloat16*)d_ws;           // 640000 bf16 = 1.28 MB

  k_zero<<<(NN + 255) / 256, 256, 0, stream>>>(cnt);
  k_count<<<(E + 255) / 256, 256, 0, stream>>>(dst, E, cnt);
  k_scan<<<1, 1024, 0, stream>>>(cnt, E, off, cursor, dis);
  k_scatter<<<(E + 255) / 256, 256, 0, stream>>>(src, dst, E, cursor, csr);

  k_gemm<INDIM><<<NN / 4, 256, 0, stream>>>(x, W1, dis, xwA);
  k_agg<true, false><<<NN / 4, 256, 0, stream>>>(xwA, off, csr, dis, b1, hB);
  k_gemm<HID><<<NN / 4, 256, 0, stream>>>(hB, W2, dis, xwA);
  k_agg<false, true><<<NN / 4, 256, 0, stream>>>(xwA, off, csr, dis, b2, h2b);

  const int T = (NN + 63) / 64;           // 157
  dim3 gf((T + 1) / 2, (T + 1) / 2);      // 79 x 79, 2x2 waves of 64x64 each
  k_final<<<gf, 256, 0, stream>>>((const short*)h2b, (float*)d_out);
}

// Round 3
// 210.774 us; speedup vs baseline: 1.4882x; 1.1807x over previous
//
#include <hip/hip_runtime.h>
#include <hip/hip_bf16.h>

#define NN 10000
#define INDIM 128
#define HID 64

typedef __attribute__((ext_vector_type(8))) short bf16x8;
typedef __attribute__((ext_vector_type(4))) float f32x4;

// ---- CSR build ----
__global__ void k_zero(int* __restrict__ cnt) {
  int i = blockIdx.x * 256 + threadIdx.x;
  if (i < NN) cnt[i] = 0;
}

__global__ void k_count(const int* __restrict__ dst, int E, int* __restrict__ cnt) {
  int e = blockIdx.x * 256 + threadIdx.x;
  if (e < E) atomicAdd(&cnt[dst[e]], 1);
}

// single-block scan over NN=10000 counts; shfl-based (2 barriers instead of 20).
// Also emits cursor copy and deg^-1/2.
__global__ __launch_bounds__(1024) void k_scan(const int* __restrict__ cnt, int E,
                                               int* __restrict__ off, int* __restrict__ cursor,
                                               float* __restrict__ dis) {
  __shared__ int wsum[16];
  int t = threadIdx.x, lane = t & 63, wid = t >> 6;
  const int CH = (NN + 1023) / 1024;  // 10
  int base = t * CH;
  int s = 0;
  #pragma unroll
  for (int i = 0; i < CH; i++) { int idx = base + i; if (idx < NN) s += cnt[idx]; }
  // wave-inclusive scan of per-thread sums
  int xs = s;
  #pragma unroll
  for (int d = 1; d < 64; d <<= 1) {
    int v = __shfl_up(xs, d, 64);
    if (lane >= d) xs += v;
  }
  if (lane == 63) wsum[wid] = xs;
  __syncthreads();
  if (wid == 0) {
    int w = (lane < 16) ? wsum[lane] : 0;
    #pragma unroll
    for (int d = 1; d < 16; d <<= 1) {
      int v = __shfl_up(w, d, 64);
      if (lane >= d) w += v;
    }
    if (lane < 16) wsum[lane] = w;   // inclusive per-wave totals
  }
  __syncthreads();
  int run = ((wid > 0) ? wsum[wid - 1] : 0) + (xs - s);  // global exclusive prefix
  #pragma unroll
  for (int i = 0; i < CH; i++) {
    int idx = base + i;
    if (idx < NN) {
      off[idx] = run;
      cursor[idx] = run;
      int c = cnt[idx];
      dis[idx] = rsqrtf((float)(c + 1));  // +1 = self loop; always > 0
      run += c;
    }
  }
  if (t == 0) off[NN] = E;
}

__global__ void k_scatter(const int* __restrict__ src, const int* __restrict__ dst, int E,
                          int* __restrict__ cursor, int* __restrict__ csr) {
  int e = blockIdx.x * 256 + threadIdx.x;
  if (e < E) {
    int p = atomicAdd(&cursor[dst[e]], 1);
    csr[p] = src[e];
  }
}

// ---- xws[r][j] = dis[r] * sum_k x[r][k] * W[k][j] ; one wave per row ----
// Row x[r] loaded once per wave as coalesced float2; inner loop broadcasts via
// compile-time-lane __shfl -> no global latency in the FMA chain.
template <int K>
__global__ __launch_bounds__(256) void k_gemm(const float* __restrict__ x,
                                              const float* __restrict__ W,
                                              const float* __restrict__ dis,
                                              float* __restrict__ xws) {
  __shared__ float w[K * HID];
  int t = threadIdx.x;
  for (int i = t; i < K * HID; i += 256) w[i] = W[i];
  __syncthreads();
  int r = blockIdx.x * 4 + (t >> 6);
  int j = t & 63;
  float2 xv = ((const float2*)(x + (size_t)r * K))[j & (K / 2 - 1)];
  float acc = 0.f;
  #pragma unroll
  for (int k = 0; k < K; k++) {
    float xk = __shfl((k & 1) ? xv.y : xv.x, k >> 1, 64);
    acc = fmaf(xk, w[k * HID + j], acc);
  }
  xws[(size_t)r * HID + j] = acc * dis[r];
}

// ---- aggregation: h[d] = dis[d]*(xws[d] + sum_in xws[s]) + b ; one wave per node ----
template <bool RELU, bool BF16OUT>
__global__ __launch_bounds__(256) void k_agg(const float* __restrict__ xws,
                                             const int* __restrict__ off,
                                             const int* __restrict__ csr,
                                             const float* __restrict__ dis,
                                             const float* __restrict__ b,
                                             void* __restrict__ hout) {
  int wid = threadIdx.x >> 6, lane = threadIdx.x & 63;
  int d = blockIdx.x * 4 + wid;
  int s0 = off[d], s1 = off[d + 1];
  float acc = xws[(size_t)d * HID + lane];   // self-loop term
  int k = s0;
  for (; k + 4 <= s1; k += 4) {              // 4-deep to break the latency chain
    int i0 = csr[k], i1 = csr[k + 1], i2 = csr[k + 2], i3 = csr[k + 3];
    float v0 = xws[(size_t)i0 * HID + lane];
    float v1 = xws[(size_t)i1 * HID + lane];
    float v2 = xws[(size_t)i2 * HID + lane];
    float v3 = xws[(size_t)i3 * HID + lane];
    acc += v0 + v1 + v2 + v3;
  }
  for (; k < s1; k++) acc += xws[(size_t)csr[k] * HID + lane];
  float v = acc * dis[d] + b[lane];
  if (RELU) v = fmaxf(v, 0.f);
  if (BF16OUT)
    ((__hip_bfloat16*)hout)[(size_t)d * HID + lane] = __float2bfloat16(v);
  else
    ((float*)hout)[(size_t)d * HID + lane] = v;
}

// ---- final: out = sigmoid(h2 @ h2^T) ----
// One wave per 64x64 output tile (4x4 accs of 16x16x32 MFMA, K=64). Z is
// symmetric: each 16x16 subtile is stored transposed -> contiguous float4 per
// lane, 16 rows x 64B per store. rt-INNER ordering issues the four 64B
// segments of each row's 256B run back-to-back so L2 merges full 128B lines
// (regular cached stores; nontemporal streamed 64B partials at ~half write
// efficiency -- the R2 bottleneck).
__global__ __launch_bounds__(256) void k_final(const short* __restrict__ hb,
                                               float* __restrict__ out) {
  const int T = (NN + 63) / 64;  // 157
  int wid = threadIdx.x >> 6, lane = threadIdx.x & 63;
  int tx = blockIdx.x * 2 + (wid & 1);
  int ty = blockIdx.y * 2 + (wid >> 1);
  if (tx >= T || ty >= T) return;
  int rowbase = tx * 64, colbase = ty * 64;
  int m = lane & 15, q = lane >> 4;

  bf16x8 a0[4], a1[4], b0[4], b1[4];
  #pragma unroll
  for (int rt = 0; rt < 4; rt++) {
    int r = rowbase + rt * 16 + m; r = r < NN ? r : NN - 1;
    const bf16x8* p = reinterpret_cast<const bf16x8*>(hb + (size_t)r * HID + q * 8);
    a0[rt] = p[0]; a1[rt] = p[4];
  }
  #pragma unroll
  for (int ct = 0; ct < 4; ct++) {
    int r = colbase + ct * 16 + m; r = r < NN ? r : NN - 1;
    const bf16x8* p = reinterpret_cast<const bf16x8*>(hb + (size_t)r * HID + q * 8);
    b0[ct] = p[0]; b1[ct] = p[4];
  }

  f32x4 acc[4][4];
  #pragma unroll
  for (int rt = 0; rt < 4; rt++)
    #pragma unroll
    for (int ct = 0; ct < 4; ct++) {
      f32x4 z = {0.f, 0.f, 0.f, 0.f};
      z = __builtin_amdgcn_mfma_f32_16x16x32_bf16(a0[rt], b0[ct], z, 0, 0, 0);
      z = __builtin_amdgcn_mfma_f32_16x16x32_bf16(a1[rt], b1[ct], z, 0, 0, 0);
      acc[rt][ct] = z;
    }

  // D[row][col]: row = rowbase+rt*16+4q+r (A side), col = colbase+ct*16+m (B side).
  // Transposed store (Z^T == Z): out[col][row]. ct outer, rt inner.
  #pragma unroll
  for (int ct = 0; ct < 4; ct++)
    #pragma unroll
    for (int rt = 0; rt < 4; rt++) {
      if (rowbase + rt * 16 < NN && colbase + ct * 16 < NN) {  // wave-uniform
        f32x4 z = acc[rt][ct], o;
        #pragma unroll
        for (int r = 0; r < 4; r++)
          o[r] = __builtin_amdgcn_rcpf(1.0f + __expf(-z[r]));
        size_t orow = (size_t)(colbase + ct * 16 + m);
        size_t ocol = (size_t)(rowbase + rt * 16 + q * 4);
        *reinterpret_cast<f32x4*>(out + orow * NN + ocol) = o;
      }
    }
}

extern "C" void kernel_launch(void* const* d_in, const int* in_sizes, int n_in,
                              void* d_out, int out_size, void* d_ws, size_t ws_size,
                              hipStream_t stream) {
  const float* x  = (const float*)d_in[0];
  const int*   ei = (const int*)d_in[1];
  const float* W1 = (const float*)d_in[2];
  const float* b1 = (const float*)d_in[3];
  const float* W2 = (const float*)d_in[4];
  const float* b2 = (const float*)d_in[5];
  const int E = in_sizes[1] / 2;
  const int* src = ei;
  const int* dst = ei + E;

  // Scratch layout inside d_out (400 MB; everything here is dead before k_final
  // rewrites all of d_out). Only h2(bf16) must live in d_ws: it is read while
  // d_out is being written.
  char* base = (char*)d_out;
  float* xwA  = (float*)(base);                          // 640000 f32 (xw scaled)
  float* hB   = (float*)(base + 2560000);                // 640000 f32 (h1)
  int*   csr  = (int*)(base + 5120000);                  // E ints
  char*  p2   = base + 5120000 + 4 * (size_t)E;
  int*   cnt    = (int*)(p2);
  int*   off    = (int*)(p2 + 40064);
  int*   cursor = (int*)(p2 + 80128);
  float* dis    = (float*)(p2 + 120192);
  __hip_bfloat16* h2b = (__hip_bfloat16*)d_ws;           // 640000 bf16 = 1.28 MB

  k_zero<<<(NN + 255) / 256, 256, 0, stream>>>(cnt);
  k_count<<<(E + 255) / 256, 256, 0, stream>>>(dst, E, cnt);
  k_scan<<<1, 1024, 0, stream>>>(cnt, E, off, cursor, dis);
  k_scatter<<<(E + 255) / 256, 256, 0, stream>>>(src, dst, E, cursor, csr);

  k_gemm<INDIM><<<NN / 4, 256, 0, stream>>>(x, W1, dis, xwA);
  k_agg<true, false><<<NN / 4, 256, 0, stream>>>(xwA, off, csr, dis, b1, hB);
  k_gemm<HID><<<NN / 4, 256, 0, stream>>>(hB, W2, dis, xwA);
  k_agg<false, true><<<NN / 4, 256, 0, stream>>>(xwA, off, csr, dis, b2, h2b);

  const int T = (NN + 63) / 64;           // 157
  dim3 gf((T + 1) / 2, (T + 1) / 2);      // 79 x 79, 2x2 waves of 64x64 each
  k_final<<<gf, 256, 0, stream>>>((const short*)h2b, (float*)d_out);
}